// Round 4
// baseline (4370.324 us; speedup 1.0000x reference)
//
#include <hip/hip_runtime.h>
#include <stdint.h>

#define NEGV   (-1000000000.0f)
#define CONF   0.05f
#define MAXSEL 550
#define CAP    32768
#define WIN    2048

__device__ __forceinline__ float areaf(float4 b) {
    return __fmul_rn(fmaxf(__fsub_rn(b.z, b.x), 0.0f), fmaxf(__fsub_rn(b.w, b.y), 0.0f));
}

// Exact predicate for: __fdiv_rn(inter, max(uni,1e-8)) > 0.15f.
// q_rn > 0.15f  <=>  exact quotient > M, M = midpoint(0.15f, next(0.15f)) = 0.15f + 2^-27
// (tie q==M rounds to even = 0.15f -> false, matching strict >).
// inter (24b) * M (25b) exact in double; comparison exact. No v_div sequence.
__device__ __forceinline__ bool iou_gt2(float4 a, float aA, float4 b, float aB) {
    float ltx = fmaxf(a.x, b.x), lty = fmaxf(a.y, b.y);
    float rbx = fminf(a.z, b.z), rby = fminf(a.w, b.w);
    float wx = fmaxf(__fsub_rn(rbx, ltx), 0.0f);
    float wy = fmaxf(__fsub_rn(rby, lty), 0.0f);
    float inter = __fmul_rn(wx, wy);
    float uni = fmaxf(__fsub_rn(__fadd_rn(aA, aB), inter), 1e-8f);
    const double M = (double)0.15f + 0x1p-27;
    return (double)inter > M * (double)uni;
}

__global__ void k_decode(const float* __restrict__ pred, float4* __restrict__ boxes, int BN) {
    int t = blockIdx.x * 256 + threadIdx.x;
    if (t >= BN) return;
    const float* p = pred + (size_t)t * 6;
    float cx = p[0], cy = p[1], w = p[2], h = p[3];
    float hw = __fmul_rn(w, 0.5f), hh = __fmul_rn(h, 0.5f);
    float4 b;
    b.x = __fsub_rn(cx, hw);
    b.y = __fsub_rn(cy, hh);
    b.z = __fadd_rn(cx, hw);
    b.w = __fadd_rn(cy, hh);
    boxes[t] = b;
}

__global__ void k_init(unsigned long long* __restrict__ keys) {
    int t = blockIdx.x * 256 + threadIdx.x;
    keys[t] = ~0ull;
}

// parallel compaction: count per 256-tile
__global__ __launch_bounds__(256) void k_cnt(const float* __restrict__ pred,
                                             unsigned int* __restrict__ tilecnt,
                                             int Nn, int Cc, int TIL) {
    int bt = blockIdx.x;
    int tile = bt % TIL, bc = bt / TIL;
    int b = bc / Cc, c = bc % Cc;
    int n = tile * 256 + threadIdx.x;
    bool p = false;
    if (n < Nn) {
        float lg = pred[((size_t)b * Nn + n) * 6 + 4 + c];
        float sc = __fdiv_rn(1.0f, __fadd_rn(1.0f, expf(-lg)));
        p = sc > CONF;
    }
    unsigned long long m = __ballot(p);
    __shared__ unsigned int wsum[4];
    if ((threadIdx.x & 63) == 0) wsum[threadIdx.x >> 6] = (unsigned)__popcll(m);
    __syncthreads();
    if (threadIdx.x == 0) tilecnt[bc * TIL + tile] = wsum[0] + wsum[1] + wsum[2] + wsum[3];
}

__global__ void k_scan(const unsigned int* __restrict__ tilecnt, unsigned int* __restrict__ tilebase,
                       unsigned int* __restrict__ cnt, int TIL, int NBC) {
    int bc = threadIdx.x;
    if (bc < NBC) {
        unsigned run = 0;
        for (int t = 0; t < TIL; ++t) { tilebase[bc * TIL + t] = run; run += tilecnt[bc * TIL + t]; }
        cnt[bc] = run < CAP ? run : CAP;
    }
}

__global__ __launch_bounds__(256) void k_write(const float* __restrict__ pred,
                                               const unsigned int* __restrict__ tilebase,
                                               unsigned long long* __restrict__ keys,
                                               int Nn, int Cc, int TIL) {
    int bt = blockIdx.x;
    int tile = bt % TIL, bc = bt / TIL;
    int b = bc / Cc, c = bc % Cc;
    int n = tile * 256 + threadIdx.x;
    bool p = false;
    float sc = 0.f;
    if (n < Nn) {
        float lg = pred[((size_t)b * Nn + n) * 6 + 4 + c];
        sc = __fdiv_rn(1.0f, __fadd_rn(1.0f, expf(-lg)));
        p = sc > CONF;
    }
    unsigned long long m = __ballot(p);
    __shared__ unsigned int wbase[4];
    int wid = threadIdx.x >> 6, lane = threadIdx.x & 63;
    if (lane == 0) wbase[wid] = (unsigned)__popcll(m);
    __syncthreads();
    if (threadIdx.x == 0) {
        unsigned run = 0;
        for (int i = 0; i < 4; ++i) { unsigned t2 = wbase[i]; wbase[i] = run; run += t2; }
    }
    __syncthreads();
    if (p) {
        unsigned pos = tilebase[bc * TIL + tile] + wbase[wid] +
                       (unsigned)__popcll(m & ((1ull << lane) - 1ull));
        if (pos < CAP)
            keys[(size_t)bc * CAP + pos] =
                (((unsigned long long)(~__float_as_uint(sc))) << 32) | (unsigned)n;
    }
}

// bitonic: local full sort of 4096-key tiles in LDS
__global__ __launch_bounds__(1024) void k_sort_local(unsigned long long* __restrict__ keys) {
    __shared__ unsigned long long sk[4096];
    unsigned long long* a = keys + (size_t)blockIdx.x * 4096;
    int lbase = (blockIdx.x & 7) * 4096;
    for (int i = threadIdx.x; i < 4096; i += 1024) sk[i] = a[i];
    __syncthreads();
    for (int k = 2; k <= 4096; k <<= 1) {
        for (int j = k >> 1; j > 0; j >>= 1) {
            for (int idx = threadIdx.x; idx < 2048; idx += 1024) {
                int i = ((idx & ~(j - 1)) << 1) | (idx & (j - 1));
                int p = i | j;
                bool up = (((lbase + i) & k) == 0);
                unsigned long long x = sk[i], y = sk[p];
                if ((x > y) == up) { sk[i] = y; sk[p] = x; }
            }
            __syncthreads();
        }
    }
    for (int i = threadIdx.x; i < 4096; i += 1024) a[i] = sk[i];
}

// bitonic: one global pass (j >= 4096)
__global__ __launch_bounds__(1024) void k_sort_global(unsigned long long* __restrict__ keys, int j, int k) {
    int idx = blockIdx.x * 1024 + threadIdx.x;
    int bc = idx >> 14;
    int lp = idx & 16383;
    int i = ((lp & ~(j - 1)) << 1) | (lp & (j - 1));
    bool up = ((i & k) == 0);
    unsigned long long* a = keys + (size_t)bc * CAP;
    unsigned long long x = a[i], y = a[i | j];
    if ((x > y) == up) { a[i] = y; a[i | j] = x; }
}

// bitonic: remaining j<=2048 stages of merge step k, in LDS per 4096-tile
__global__ __launch_bounds__(1024) void k_sort_mergelds(unsigned long long* __restrict__ keys, int k) {
    __shared__ unsigned long long sk[4096];
    unsigned long long* a = keys + (size_t)blockIdx.x * 4096;
    int lbase = (blockIdx.x & 7) * 4096;
    bool up = ((lbase & k) == 0);
    for (int i = threadIdx.x; i < 4096; i += 1024) sk[i] = a[i];
    __syncthreads();
    for (int j = 2048; j > 0; j >>= 1) {
        for (int idx = threadIdx.x; idx < 2048; idx += 1024) {
            int i = ((idx & ~(j - 1)) << 1) | (idx & (j - 1));
            int p = i | j;
            unsigned long long x = sk[i], y = sk[p];
            if ((x > y) == up) { sk[i] = y; sk[p] = x; }
        }
        __syncthreads();
    }
    for (int i = threadIdx.x; i < 4096; i += 1024) a[i] = sk[i];
}

// Lazy single-wave greedy NMS. One 256-thread block per (b,c).
// All 4 waves stage WIN sorted candidates into LDS (+ eager test vs selected-so-far);
// wave 0 then pops first-alive candidates from a register-resident bitmask and tests
// each popped candidate 64-lane-parallel against the selected set. No block-wide
// work per selection, no division.
__global__ __launch_bounds__(256) void k_nms(const unsigned long long* __restrict__ keys,
                                             const unsigned int* __restrict__ cnt,
                                             const float4* __restrict__ boxes,
                                             unsigned int* __restrict__ sel_n,
                                             float* __restrict__ sel_s,
                                             unsigned int* __restrict__ selcnt,
                                             int Nn, int Cc) {
    int bc = blockIdx.x, b = bc / Cc;
    int tid = threadIdx.x, lane = tid & 63, wv = tid >> 6;
    __shared__ float4 wbox[WIN];            // 32 KB
    __shared__ float  war[WIN];             // 8 KB
    __shared__ unsigned wn[WIN];            // 8 KB
    __shared__ float  wsc[WIN];             // 8 KB
    __shared__ unsigned long long alive[WIN / 64];
    __shared__ float4 selb[MAXSEL];         // 8.8 KB
    __shared__ float  sela[MAXSEL];
    __shared__ int s_S;
    int cv = (int)cnt[bc];
    const unsigned long long* kk = keys + (size_t)bc * CAP;
    if (tid == 0) s_S = 0;
    __syncthreads();
    for (int base = 0; base < cv; base += WIN) {
        int S0 = s_S;
        // ---- stage: 8 rounds of 256 consecutive slots; wave wv round r covers word r*4+wv
        for (int r = 0; r < 8; ++r) {
            int idx = (r << 8) + tid;
            int g = base + idx;
            bool al = g < cv;
            if (al) {
                unsigned long long key = kk[g];
                unsigned n = (unsigned)key;
                float4 bx = boxes[(size_t)b * Nn + n];
                float aA = areaf(bx);
                wbox[idx] = bx; war[idx] = aA;
                wn[idx] = n; wsc[idx] = __uint_as_float(~(unsigned)(key >> 32));
                for (int s = 0; s < S0; ++s)
                    if (iou_gt2(selb[s], sela[s], bx, aA)) { al = false; break; }
            }
            unsigned long long m = __ballot(al);
            if (lane == 0) alive[(r << 2) + wv] = m;
        }
        __syncthreads();
        // ---- chain: wave 0 only
        if (tid < 64) {
            unsigned long long word = (lane < 32) ? alive[lane] : 0ull;
            int S = S0;
            for (;;) {
                unsigned long long mm = __ballot(word != 0ull);
                if (!mm) break;                          // window exhausted
                int w0 = __builtin_ctzll(mm);
                unsigned long long ww = __shfl(word, w0);
                int kz = __builtin_ctzll(ww);
                if (lane == w0) word &= word - 1ull;     // clear lowest set bit
                int i = (w0 << 6) + kz;
                float4 cb = wbox[i];                     // LDS broadcast
                float ca = war[i];
                bool ov = false;
                for (int t = S0 + lane; t < S; t += 64)  // selections since window stage
                    if (iou_gt2(cb, ca, selb[t], sela[t])) { ov = true; break; }
                if (__ballot(ov) == 0ull) {
                    if (lane == 0) {
                        selb[S] = cb; sela[S] = ca;
                        sel_n[bc * MAXSEL + S] = wn[i];
                        sel_s[bc * MAXSEL + S] = wsc[i];
                    }
                    ++S;
                    if (S >= MAXSEL) break;
                }
            }
            if (lane == 0) s_S = S;
        }
        __syncthreads();
        if (s_S >= MAXSEL) break;
    }
    if (tid == 0) selcnt[bc] = (unsigned)s_S;
}

// final: per-batch full sort of C*550 entries (== top_k) + output write
__global__ __launch_bounds__(1024) void k_final(const unsigned int* __restrict__ selcnt,
                                                const unsigned int* __restrict__ sel_n,
                                                const float* __restrict__ sel_s,
                                                const float4* __restrict__ boxes,
                                                float* __restrict__ out,
                                                int Nn, int Cc, int Bb) {
    int b = blockIdx.x, tid = threadIdx.x;
    const int TOT = MAXSEL * 2;   // 1100
    __shared__ unsigned long long sk[2048];
    unsigned c0 = selcnt[b * Cc + 0];
    unsigned c1 = selcnt[b * Cc + 1];
    for (int t = tid; t < 2048; t += 1024) {
        unsigned long long key;
        if (t < TOT) {
            int c = t / MAXSEL, k2 = t % MAXSEL;
            unsigned cc = (c == 0) ? c0 : c1;
            float sc = (k2 < (int)cc) ? sel_s[(size_t)(b * Cc + c) * MAXSEL + k2] : NEGV;
            unsigned u = __float_as_uint(sc);
            unsigned ord = (u & 0x80000000u) ? ~u : (u | 0x80000000u);
            key = (((unsigned long long)(~ord)) << 32) | (unsigned)t;
        } else {
            key = ~0ull;
        }
        sk[t] = key;
    }
    __syncthreads();
    for (int k = 2; k <= 2048; k <<= 1) {
        for (int j = k >> 1; j > 0; j >>= 1) {
            int idx = tid;
            int i = ((idx & ~(j - 1)) << 1) | (idx & (j - 1));
            int p = i | j;
            bool up = ((i & k) == 0);
            unsigned long long x = sk[i], y = sk[p];
            if ((x > y) == up) { sk[i] = y; sk[p] = x; }
            __syncthreads();
        }
    }
    int off_scores = Bb * TOT * 4;
    int off_classes = off_scores + Bb * TOT;
    int off_valid = off_classes + Bb * TOT;
    for (int r = tid; r < TOT; r += 1024) {
        unsigned long long key = sk[r];
        unsigned flat = (unsigned)(key & 0xffffffffull);
        unsigned hi = (unsigned)(key >> 32);
        unsigned ord = ~hi;
        float sc = (ord & 0x80000000u) ? __uint_as_float(ord & 0x7fffffffu)
                                       : __uint_as_float(~ord);
        bool valid = sc > -5.0e8f;
        int c = (int)(flat / MAXSEL), k2 = (int)(flat % MAXSEL);
        float4 bxv = make_float4(0.f, 0.f, 0.f, 0.f);
        float so = 0.f, co = 0.f;
        if (valid) {
            unsigned n = sel_n[(size_t)(b * Cc + c) * MAXSEL + k2];
            bxv = boxes[(size_t)b * Nn + n];
            so = sc;
            co = (float)c;
        }
        ((float4*)out)[b * TOT + r] = bxv;
        out[off_scores + b * TOT + r] = so;
        out[off_classes + b * TOT + r] = co;
    }
    if (tid == 0) out[off_valid + b] = (float)(c0 + c1);
}

extern "C" void kernel_launch(void* const* d_in, const int* in_sizes, int n_in,
                              void* d_out, int out_size, void* d_ws, size_t ws_size,
                              hipStream_t stream) {
    const float* pred = (const float*)d_in[1];
    float* out = (float*)d_out;
    int Bb = out_size / 6601;            // 4
    int Nn = in_sizes[1] / (6 * Bb);     // 49104
    const int Cc = 2;
    if (Bb <= 0 || Nn <= 0) return;
    int NBC = Bb * Cc;                   // 8
    int TIL = (Nn + 255) / 256;          // 192

    char* ws = (char*)d_ws;
    size_t off = 0;
    auto alloc = [&](size_t bytes) { void* p = ws + off; off = (off + bytes + 255) & ~(size_t)255; return p; };
    float4* boxes            = (float4*)alloc((size_t)Bb * Nn * 16);
    unsigned long long* keys = (unsigned long long*)alloc((size_t)NBC * CAP * 8);
    unsigned int* cnt        = (unsigned int*)alloc(NBC * 4);
    unsigned int* tilecnt    = (unsigned int*)alloc((size_t)NBC * TIL * 4);
    unsigned int* tilebase   = (unsigned int*)alloc((size_t)NBC * TIL * 4);
    unsigned int* sel_n      = (unsigned int*)alloc((size_t)NBC * MAXSEL * 4);
    float* sel_s             = (float*)alloc((size_t)NBC * MAXSEL * 4);
    unsigned int* selcnt     = (unsigned int*)alloc(NBC * 4);
    if (off > ws_size) return;

    int BN = Bb * Nn;
    k_init<<<NBC * CAP / 256, 256, 0, stream>>>(keys);
    k_decode<<<(BN + 255) / 256, 256, 0, stream>>>(pred, boxes, BN);
    k_cnt<<<NBC * TIL, 256, 0, stream>>>(pred, tilecnt, Nn, Cc, TIL);
    k_scan<<<1, 64, 0, stream>>>(tilecnt, tilebase, cnt, TIL, NBC);
    k_write<<<NBC * TIL, 256, 0, stream>>>(pred, tilebase, keys, Nn, Cc, TIL);

    int ntiles = NBC * (CAP / 4096);     // 64
    k_sort_local<<<ntiles, 1024, 0, stream>>>(keys);
    for (int k = 8192; k <= CAP; k <<= 1) {
        for (int j = k >> 1; j >= 4096; j >>= 1)
            k_sort_global<<<NBC * (CAP / 2) / 1024, 1024, 0, stream>>>(keys, j, k);
        k_sort_mergelds<<<ntiles, 1024, 0, stream>>>(keys, k);
    }

    k_nms<<<NBC, 256, 0, stream>>>(keys, cnt, boxes, sel_n, sel_s, selcnt, Nn, Cc);
    k_final<<<Bb, 1024, 0, stream>>>(selcnt, sel_n, sel_s, boxes, out, Nn, Cc, Bb);
}

// Round 5
// 1210.546 us; speedup vs baseline: 3.6102x; 3.6102x over previous
//
#include <hip/hip_runtime.h>
#include <stdint.h>

#define NEGV    (-1000000000.0f)
#define CONF    0.05f
#define MAXSEL  550
#define CAP     32768
#define WIN     4096
#define SEG     16
#define SEGLEN  (CAP / SEG)    // 2048
#define TROUNDS 5
#define INFI    0x7fffffff

typedef unsigned long long u64;
typedef unsigned int u32;

__device__ __forceinline__ float areaf(float4 b) {
    return __fmul_rn(fmaxf(__fsub_rn(b.z, b.x), 0.0f), fmaxf(__fsub_rn(b.w, b.y), 0.0f));
}

// Exact predicate for: __fdiv_rn(inter, max(uni,1e-8)) > 0.15f  (verified absmax 0 in R4).
// q_rn > 0.15f  <=>  exact quotient > M, M = midpoint(0.15f, next(0.15f)) = 0.15f + 2^-27.
// inter (24b) * M (25b) exact in double; comparison exact. No v_div sequence.
__device__ __forceinline__ bool iou_gt2(float4 a, float aA, float4 b, float aB) {
    float ltx = fmaxf(a.x, b.x), lty = fmaxf(a.y, b.y);
    float rbx = fminf(a.z, b.z), rby = fminf(a.w, b.w);
    float wx = fmaxf(__fsub_rn(rbx, ltx), 0.0f);
    float wy = fmaxf(__fsub_rn(rby, lty), 0.0f);
    float inter = __fmul_rn(wx, wy);
    float uni = fmaxf(__fsub_rn(__fadd_rn(aA, aB), inter), 1e-8f);
    const double M = (double)0.15f + 0x1p-27;
    return (double)inter > M * (double)uni;
}

__global__ void k_decode(const float* __restrict__ pred, float4* __restrict__ boxes, int BN) {
    int t = blockIdx.x * 256 + threadIdx.x;
    if (t >= BN) return;
    const float* p = pred + (size_t)t * 6;
    float cx = p[0], cy = p[1], w = p[2], h = p[3];
    float hw = __fmul_rn(w, 0.5f), hh = __fmul_rn(h, 0.5f);
    float4 b;
    b.x = __fsub_rn(cx, hw);
    b.y = __fsub_rn(cy, hh);
    b.z = __fadd_rn(cx, hw);
    b.w = __fadd_rn(cy, hh);
    boxes[t] = b;
}

__global__ void k_init(u64* __restrict__ keys, u32* __restrict__ S_arr,
                       u32* __restrict__ Sold, int NBC) {
    int t = blockIdx.x * 256 + threadIdx.x;
    keys[t] = ~0ull;
    if (t < NBC) { S_arr[t] = 0; Sold[t] = 0; }
}

// parallel compaction: count per 256-tile
__global__ __launch_bounds__(256) void k_cnt(const float* __restrict__ pred,
                                             u32* __restrict__ tilecnt,
                                             int Nn, int Cc, int TIL) {
    int bt = blockIdx.x;
    int tile = bt % TIL, bc = bt / TIL;
    int b = bc / Cc, c = bc % Cc;
    int n = tile * 256 + threadIdx.x;
    bool p = false;
    if (n < Nn) {
        float lg = pred[((size_t)b * Nn + n) * 6 + 4 + c];
        float sc = __fdiv_rn(1.0f, __fadd_rn(1.0f, expf(-lg)));
        p = sc > CONF;
    }
    u64 m = __ballot(p);
    __shared__ u32 wsum[4];
    if ((threadIdx.x & 63) == 0) wsum[threadIdx.x >> 6] = (u32)__popcll(m);
    __syncthreads();
    if (threadIdx.x == 0) tilecnt[bc * TIL + tile] = wsum[0] + wsum[1] + wsum[2] + wsum[3];
}

__global__ void k_scan(const u32* __restrict__ tilecnt, u32* __restrict__ tilebase,
                       u32* __restrict__ llen0, int TIL, int NBC) {
    int bc = threadIdx.x;
    if (bc < NBC) {
        u32 run = 0;
        for (int t = 0; t < TIL; ++t) { tilebase[bc * TIL + t] = run; run += tilecnt[bc * TIL + t]; }
        llen0[bc] = run < CAP ? run : CAP;
    }
}

__global__ __launch_bounds__(256) void k_write(const float* __restrict__ pred,
                                               const u32* __restrict__ tilebase,
                                               u64* __restrict__ keys,
                                               int Nn, int Cc, int TIL) {
    int bt = blockIdx.x;
    int tile = bt % TIL, bc = bt / TIL;
    int b = bc / Cc, c = bc % Cc;
    int n = tile * 256 + threadIdx.x;
    bool p = false;
    float sc = 0.f;
    if (n < Nn) {
        float lg = pred[((size_t)b * Nn + n) * 6 + 4 + c];
        sc = __fdiv_rn(1.0f, __fadd_rn(1.0f, expf(-lg)));
        p = sc > CONF;
    }
    u64 m = __ballot(p);
    __shared__ u32 wbase[4];
    int wid = threadIdx.x >> 6, lane = threadIdx.x & 63;
    if (lane == 0) wbase[wid] = (u32)__popcll(m);
    __syncthreads();
    if (threadIdx.x == 0) {
        u32 run = 0;
        for (int i = 0; i < 4; ++i) { u32 t2 = wbase[i]; wbase[i] = run; run += t2; }
    }
    __syncthreads();
    if (p) {
        u32 pos = tilebase[bc * TIL + tile] + wbase[wid] +
                  (u32)__popcll(m & ((1ull << lane) - 1ull));
        if (pos < CAP)
            keys[(size_t)bc * CAP + pos] =
                (((u64)(~__float_as_uint(sc))) << 32) | (u32)n;
    }
}

// bitonic: local full sort of 4096-key tiles in LDS
__global__ __launch_bounds__(1024) void k_sort_local(u64* __restrict__ keys) {
    __shared__ u64 sk[4096];
    u64* a = keys + (size_t)blockIdx.x * 4096;
    int lbase = (blockIdx.x & 7) * 4096;
    for (int i = threadIdx.x; i < 4096; i += 1024) sk[i] = a[i];
    __syncthreads();
    for (int k = 2; k <= 4096; k <<= 1) {
        for (int j = k >> 1; j > 0; j >>= 1) {
            for (int idx = threadIdx.x; idx < 2048; idx += 1024) {
                int i = ((idx & ~(j - 1)) << 1) | (idx & (j - 1));
                int p = i | j;
                bool up = (((lbase + i) & k) == 0);
                u64 x = sk[i], y = sk[p];
                if ((x > y) == up) { sk[i] = y; sk[p] = x; }
            }
            __syncthreads();
        }
    }
    for (int i = threadIdx.x; i < 4096; i += 1024) a[i] = sk[i];
}

// bitonic: one global pass (j >= 4096)
__global__ __launch_bounds__(1024) void k_sort_global(u64* __restrict__ keys, int j, int k) {
    int idx = blockIdx.x * 1024 + threadIdx.x;
    int bc = idx >> 14;
    int lp = idx & 16383;
    int i = ((lp & ~(j - 1)) << 1) | (lp & (j - 1));
    bool up = ((i & k) == 0);
    u64* a = keys + (size_t)bc * CAP;
    u64 x = a[i], y = a[i | j];
    if ((x > y) == up) { a[i] = y; a[i | j] = x; }
}

// bitonic: remaining j<=2048 stages of merge step k, in LDS per 4096-tile
__global__ __launch_bounds__(1024) void k_sort_mergelds(u64* __restrict__ keys, int k) {
    __shared__ u64 sk[4096];
    u64* a = keys + (size_t)blockIdx.x * 4096;
    int lbase = (blockIdx.x & 7) * 4096;
    bool up = ((lbase & k) == 0);
    for (int i = threadIdx.x; i < 4096; i += 1024) sk[i] = a[i];
    __syncthreads();
    for (int j = 2048; j > 0; j >>= 1) {
        for (int idx = threadIdx.x; idx < 2048; idx += 1024) {
            int i = ((idx & ~(j - 1)) << 1) | (idx & (j - 1));
            int p = i | j;
            u64 x = sk[i], y = sk[p];
            if ((x > y) == up) { sk[i] = y; sk[p] = x; }
        }
        __syncthreads();
    }
    for (int i = threadIdx.x; i < 4096; i += 1024) a[i] = sk[i];
}

// Eager single-wave greedy NMS over one WIN-window (list head). Candidates already
// filtered vs all previous selections. Lane l owns candidates {b*64+l}. Per selection:
// shfl-min finds first alive, lanes suppress their own alive bits vs the published box.
__global__ __launch_bounds__(256) void k_chain(const u64* __restrict__ list,
                                               const u32* __restrict__ lcur,
                                               const float4* __restrict__ boxes,
                                               float4* __restrict__ selb,
                                               u32* __restrict__ sel_n,
                                               float* __restrict__ sel_s,
                                               u32* __restrict__ S_arr,
                                               u32* __restrict__ Sold,
                                               int Nn, int Cc) {
    int bc = blockIdx.x, b = bc / Cc;
    int tid = threadIdx.x, lane = tid & 63;
    __shared__ float4 wbox[WIN];   // 64 KB, rotated layout
    __shared__ u64    wk[WIN];     // 32 KB, linear
    int len = (int)lcur[bc];
    int S0 = (int)S_arr[bc];
    if (tid == 0) Sold[bc] = (u32)S0;
    int win = len < WIN ? len : WIN;
    if (win <= 0 || S0 >= MAXSEL) return;
    const u64* kk = list + (size_t)bc * CAP;
    for (int idx = tid; idx < win; idx += 256) {
        u64 key = kk[idx];
        float4 bx = boxes[(size_t)b * Nn + (u32)key];
        int bb = idx >> 6, ll = idx & 63;
        wbox[(bb << 6) | ((ll + bb) & 63)] = bx;   // rotated: banks spread for chain reads
        wk[idx] = key;
    }
    __syncthreads();
    if (tid >= 64) return;
    // alive mask: lane owns candidates b*64+lane, b=0..63
    u64 m = 0;
    if (lane < win) {
        int nb = ((win - 1 - lane) >> 6) + 1;
        m = (nb >= 64) ? ~0ull : ((1ull << nb) - 1ull);
    }
    int S = S0;
    while (S < MAXSEL) {
        int key = m ? ((__builtin_ctzll(m) << 6) | lane) : INFI;  // == candidate index
        for (int off = 32; off; off >>= 1) {
            int o = __shfl_xor(key, off);
            key = o < key ? o : key;
        }
        if (key == INFI) break;
        int i = key;
        if (lane == (i & 63)) m &= ~(1ull << (i >> 6));
        int bb = i >> 6, lo = i & 63;
        float4 cb = wbox[(bb << 6) | ((lo + bb) & 63)];   // broadcast
        float ca = areaf(cb);
        if (lane == 0) {
            u64 k64 = wk[i];
            selb[bc * MAXSEL + S] = cb;
            sel_n[bc * MAXSEL + S] = (u32)k64;
            sel_s[bc * MAXSEL + S] = __uint_as_float(~(u32)(k64 >> 32));
        }
        ++S;
        if (S >= MAXSEL) break;
        u64 mm = m;
        while (mm) {
            int bbit = __builtin_ctzll(mm);
            mm &= mm - 1ull;
            int sl = (bbit << 6) | ((lane + bbit) & 63);
            float4 bx = wbox[sl];
            if (iou_gt2(bx, areaf(bx), cb, ca)) m &= ~(1ull << bbit);
        }
    }
    if (lane == 0) S_arr[bc] = (u32)S;
}

// Parallel filter: test remaining candidates [consumed, len) vs selections added this
// round [S0, S1); write alive bitmask + per-segment survivor counts.
__global__ __launch_bounds__(256) void k_mark(const u64* __restrict__ list,
                                              const u32* __restrict__ lcur,
                                              const float4* __restrict__ boxes,
                                              const float4* __restrict__ selb,
                                              const u32* __restrict__ S_arr,
                                              const u32* __restrict__ Sold,
                                              u64* __restrict__ amask,
                                              u32* __restrict__ counts,
                                              int Nn, int Cc) {
    int blk = blockIdx.x, bc = blk >> 4, seg = blk & 15;
    int tid = threadIdx.x, lane = tid & 63, wv = tid >> 6;
    int b = bc / Cc;
    int len = (int)lcur[bc];
    int S0 = (int)Sold[bc], S1 = (int)S_arr[bc];
    int ns = S1 - S0;
    int consumed = len < WIN ? len : WIN;
    __shared__ float4 sb[MAXSEL];
    __shared__ float  sa[MAXSEL];
    for (int s = tid; s < ns; s += 256) {
        float4 v = selb[bc * MAXSEL + S0 + s];
        sb[s] = v; sa[s] = areaf(v);
    }
    __syncthreads();
    __shared__ u32 wcnt[4];
    u32 mycnt = 0;
    const u64* kk = list + (size_t)bc * CAP;
    for (int r = 0; r < SEGLEN / 256; ++r) {
        int idx = seg * SEGLEN + r * 256 + tid;
        bool alive = (idx >= consumed && idx < len);
        if (alive) {
            u64 key = kk[idx];
            float4 bx = boxes[(size_t)b * Nn + (u32)key];
            float aA = areaf(bx);
            for (int s = 0; s < ns; ++s)
                if (iou_gt2(bx, aA, sb[s], sa[s])) { alive = false; break; }
        }
        u64 bal = __ballot(alive);
        if (lane == 0) {
            amask[(size_t)bc * (CAP / 64) + (idx >> 6)] = bal;
            mycnt += (u32)__popcll(bal);
        }
    }
    if (lane == 0) wcnt[wv] = mycnt;
    __syncthreads();
    if (tid == 0) counts[bc * SEG + seg] = wcnt[0] + wcnt[1] + wcnt[2] + wcnt[3];
}

// Order-preserving compaction of survivors into the other list buffer; updates next llen.
__global__ __launch_bounds__(256) void k_cwrite(const u64* __restrict__ cur,
                                                u64* __restrict__ nxt,
                                                u32* __restrict__ lnxt,
                                                const u64* __restrict__ amask,
                                                const u32* __restrict__ counts) {
    int blk = blockIdx.x, bc = blk >> 4, seg = blk & 15;
    int tid = threadIdx.x, lane = tid & 63, wv = tid >> 6;
    __shared__ u32 sbase;
    __shared__ u32 wb[4];
    if (tid == 0) {
        u32 base = 0;
        for (int s = 0; s < seg; ++s) base += counts[bc * SEG + s];
        sbase = base;
        if (seg == 0) {
            u32 tot = 0;
            for (int s = 0; s < SEG; ++s) tot += counts[bc * SEG + s];
            lnxt[bc] = tot;
        }
    }
    __syncthreads();
    u32 run = sbase;
    const u64* src = cur + (size_t)bc * CAP;
    u64* dst = nxt + (size_t)bc * CAP;
    for (int r = 0; r < SEGLEN / 256; ++r) {
        int idx = seg * SEGLEN + r * 256 + tid;
        u64 w = amask[(size_t)bc * (CAP / 64) + (idx >> 6)];  // one word per wave (aligned)
        bool alive = (w >> lane) & 1ull;
        if (lane == 0) wb[wv] = (u32)__popcll(w);
        __syncthreads();
        u32 wpre = 0;
        #pragma unroll
        for (int i = 0; i < 4; ++i) if (i < wv) wpre += wb[i];
        if (alive) {
            u32 rank = (u32)__popcll(w & ((1ull << lane) - 1ull));
            dst[run + wpre + rank] = src[idx];
        }
        u32 tot = wb[0] + wb[1] + wb[2] + wb[3];
        __syncthreads();
        run += tot;
    }
}

// final: per-batch full sort of C*550 entries (== top_k) + output write
__global__ __launch_bounds__(1024) void k_final(const u32* __restrict__ selcnt,
                                                const u32* __restrict__ sel_n,
                                                const float* __restrict__ sel_s,
                                                const float4* __restrict__ boxes,
                                                float* __restrict__ out,
                                                int Nn, int Cc, int Bb) {
    int b = blockIdx.x, tid = threadIdx.x;
    const int TOT = MAXSEL * 2;   // 1100
    __shared__ u64 sk[2048];
    u32 c0 = selcnt[b * Cc + 0];
    u32 c1 = selcnt[b * Cc + 1];
    for (int t = tid; t < 2048; t += 1024) {
        u64 key;
        if (t < TOT) {
            int c = t / MAXSEL, k2 = t % MAXSEL;
            u32 cc = (c == 0) ? c0 : c1;
            float sc = (k2 < (int)cc) ? sel_s[(size_t)(b * Cc + c) * MAXSEL + k2] : NEGV;
            u32 u = __float_as_uint(sc);
            u32 ord = (u & 0x80000000u) ? ~u : (u | 0x80000000u);
            key = (((u64)(~ord)) << 32) | (u32)t;
        } else {
            key = ~0ull;
        }
        sk[t] = key;
    }
    __syncthreads();
    for (int k = 2; k <= 2048; k <<= 1) {
        for (int j = k >> 1; j > 0; j >>= 1) {
            int idx = tid;
            int i = ((idx & ~(j - 1)) << 1) | (idx & (j - 1));
            int p = i | j;
            bool up = ((i & k) == 0);
            u64 x = sk[i], y = sk[p];
            if ((x > y) == up) { sk[i] = y; sk[p] = x; }
            __syncthreads();
        }
    }
    int off_scores = Bb * TOT * 4;
    int off_classes = off_scores + Bb * TOT;
    int off_valid = off_classes + Bb * TOT;
    for (int r = tid; r < TOT; r += 1024) {
        u64 key = sk[r];
        u32 flat = (u32)(key & 0xffffffffull);
        u32 hi = (u32)(key >> 32);
        u32 ord = ~hi;
        float sc = (ord & 0x80000000u) ? __uint_as_float(ord & 0x7fffffffu)
                                       : __uint_as_float(~ord);
        bool valid = sc > -5.0e8f;
        int c = (int)(flat / MAXSEL), k2 = (int)(flat % MAXSEL);
        float4 bxv = make_float4(0.f, 0.f, 0.f, 0.f);
        float so = 0.f, co = 0.f;
        if (valid) {
            u32 n = sel_n[(size_t)(b * Cc + c) * MAXSEL + k2];
            bxv = boxes[(size_t)b * Nn + n];
            so = sc;
            co = (float)c;
        }
        ((float4*)out)[b * TOT + r] = bxv;
        out[off_scores + b * TOT + r] = so;
        out[off_classes + b * TOT + r] = co;
    }
    if (tid == 0) out[off_valid + b] = (float)(c0 + c1);
}

extern "C" void kernel_launch(void* const* d_in, const int* in_sizes, int n_in,
                              void* d_out, int out_size, void* d_ws, size_t ws_size,
                              hipStream_t stream) {
    const float* pred = (const float*)d_in[1];
    float* out = (float*)d_out;
    int Bb = out_size / 6601;            // 4
    int Nn = in_sizes[1] / (6 * Bb);     // 49104
    const int Cc = 2;
    if (Bb <= 0 || Nn <= 0) return;
    int NBC = Bb * Cc;                   // 8
    int TIL = (Nn + 255) / 256;          // 192

    char* ws = (char*)d_ws;
    size_t off = 0;
    auto alloc = [&](size_t bytes) { void* p = ws + off; off = (off + bytes + 255) & ~(size_t)255; return p; };
    float4* boxes   = (float4*)alloc((size_t)Bb * Nn * 16);
    u64* L0         = (u64*)alloc((size_t)NBC * CAP * 8);
    u64* L1         = (u64*)alloc((size_t)NBC * CAP * 8);
    u32* llen       = (u32*)alloc(2 * NBC * 4);            // ping-pong lengths
    u32* tilecnt    = (u32*)alloc((size_t)NBC * TIL * 4);
    u32* tilebase   = (u32*)alloc((size_t)NBC * TIL * 4);
    float4* selb    = (float4*)alloc((size_t)NBC * MAXSEL * 16);
    u32* sel_n      = (u32*)alloc((size_t)NBC * MAXSEL * 4);
    float* sel_s    = (float*)alloc((size_t)NBC * MAXSEL * 4);
    u32* S_arr      = (u32*)alloc(NBC * 4);
    u32* Sold       = (u32*)alloc(NBC * 4);
    u64* amask      = (u64*)alloc((size_t)NBC * (CAP / 64) * 8);
    u32* counts     = (u32*)alloc((size_t)NBC * SEG * 4);
    if (off > ws_size) return;

    int BN = Bb * Nn;
    k_init<<<NBC * CAP / 256, 256, 0, stream>>>(L0, S_arr, Sold, NBC);
    k_decode<<<(BN + 255) / 256, 256, 0, stream>>>(pred, boxes, BN);
    k_cnt<<<NBC * TIL, 256, 0, stream>>>(pred, tilecnt, Nn, Cc, TIL);
    k_scan<<<1, 64, 0, stream>>>(tilecnt, tilebase, llen, TIL, NBC);
    k_write<<<NBC * TIL, 256, 0, stream>>>(pred, tilebase, L0, Nn, Cc, TIL);

    int ntiles = NBC * (CAP / 4096);     // 64
    k_sort_local<<<ntiles, 1024, 0, stream>>>(L0);
    for (int k = 8192; k <= CAP; k <<= 1) {
        for (int j = k >> 1; j >= 4096; j >>= 1)
            k_sort_global<<<NBC * (CAP / 2) / 1024, 1024, 0, stream>>>(L0, j, k);
        k_sort_mergelds<<<ntiles, 1024, 0, stream>>>(L0, k);
    }

    for (int r = 0; r < TROUNDS; ++r) {
        u64* cur = (r & 1) ? L1 : L0;
        u64* nxt = (r & 1) ? L0 : L1;
        u32* lcur = llen + (r & 1) * NBC;
        u32* lnxt = llen + ((r + 1) & 1) * NBC;
        k_chain<<<NBC, 256, 0, stream>>>(cur, lcur, boxes, selb, sel_n, sel_s, S_arr, Sold, Nn, Cc);
        k_mark<<<NBC * SEG, 256, 0, stream>>>(cur, lcur, boxes, selb, S_arr, Sold, amask, counts, Nn, Cc);
        k_cwrite<<<NBC * SEG, 256, 0, stream>>>(cur, nxt, lnxt, amask, counts);
    }
    k_final<<<Bb, 1024, 0, stream>>>(S_arr, sel_n, sel_s, boxes, out, Nn, Cc, Bb);
}

// Round 6
// 549.142 us; speedup vs baseline: 7.9585x; 2.2044x over previous
//
#include <hip/hip_runtime.h>
#include <stdint.h>

#define NEGV    (-1000000000.0f)
#define CONF    0.05f
#define MAXSEL  550
#define CAP     32768
#define HEAD    1024
#define HW      (HEAD / 64)    // 16 mask words per row
#define SEG     16
#define SEGLEN  (CAP / SEG)    // 2048
#define TROUNDS 5

typedef unsigned long long u64;
typedef unsigned int u32;

__device__ __forceinline__ float areaf(float4 b) {
    return __fmul_rn(fmaxf(__fsub_rn(b.z, b.x), 0.0f), fmaxf(__fsub_rn(b.w, b.y), 0.0f));
}

// Exact predicate for: __fdiv_rn(inter, max(uni,1e-8)) > 0.15f  (verified absmax 0 since R4).
// q_rn > 0.15f  <=>  exact quotient > M, M = midpoint(0.15f, next(0.15f)) = 0.15f + 2^-27.
// inter (24b) * M (25b) exact in double; comparison exact. No v_div sequence. Symmetric in (a,b).
__device__ __forceinline__ bool iou_gt2(float4 a, float aA, float4 b, float aB) {
    float ltx = fmaxf(a.x, b.x), lty = fmaxf(a.y, b.y);
    float rbx = fminf(a.z, b.z), rby = fminf(a.w, b.w);
    float wx = fmaxf(__fsub_rn(rbx, ltx), 0.0f);
    float wy = fmaxf(__fsub_rn(rby, lty), 0.0f);
    float inter = __fmul_rn(wx, wy);
    float uni = fmaxf(__fsub_rn(__fadd_rn(aA, aB), inter), 1e-8f);
    const double M = (double)0.15f + 0x1p-27;
    return (double)inter > M * (double)uni;
}

__global__ void k_decode(const float* __restrict__ pred, float4* __restrict__ boxes, int BN) {
    int t = blockIdx.x * 256 + threadIdx.x;
    if (t >= BN) return;
    const float* p = pred + (size_t)t * 6;
    float cx = p[0], cy = p[1], w = p[2], h = p[3];
    float hw = __fmul_rn(w, 0.5f), hh = __fmul_rn(h, 0.5f);
    float4 b;
    b.x = __fsub_rn(cx, hw);
    b.y = __fsub_rn(cy, hh);
    b.z = __fadd_rn(cx, hw);
    b.w = __fadd_rn(cy, hh);
    boxes[t] = b;
}

__global__ void k_init(u64* __restrict__ keys, u32* __restrict__ S_arr,
                       u32* __restrict__ Sold, int NBC) {
    int t = blockIdx.x * 256 + threadIdx.x;
    keys[t] = ~0ull;
    if (t < NBC) { S_arr[t] = 0; Sold[t] = 0; }
}

// parallel compaction: count per 256-tile
__global__ __launch_bounds__(256) void k_cnt(const float* __restrict__ pred,
                                             u32* __restrict__ tilecnt,
                                             int Nn, int Cc, int TIL) {
    int bt = blockIdx.x;
    int tile = bt % TIL, bc = bt / TIL;
    int b = bc / Cc, c = bc % Cc;
    int n = tile * 256 + threadIdx.x;
    bool p = false;
    if (n < Nn) {
        float lg = pred[((size_t)b * Nn + n) * 6 + 4 + c];
        float sc = __fdiv_rn(1.0f, __fadd_rn(1.0f, expf(-lg)));
        p = sc > CONF;
    }
    u64 m = __ballot(p);
    __shared__ u32 wsum[4];
    if ((threadIdx.x & 63) == 0) wsum[threadIdx.x >> 6] = (u32)__popcll(m);
    __syncthreads();
    if (threadIdx.x == 0) tilecnt[bc * TIL + tile] = wsum[0] + wsum[1] + wsum[2] + wsum[3];
}

__global__ void k_scan(const u32* __restrict__ tilecnt, u32* __restrict__ tilebase,
                       u32* __restrict__ llen0, int TIL, int NBC) {
    int bc = threadIdx.x;
    if (bc < NBC) {
        u32 run = 0;
        for (int t = 0; t < TIL; ++t) { tilebase[bc * TIL + t] = run; run += tilecnt[bc * TIL + t]; }
        llen0[bc] = run < CAP ? run : CAP;
    }
}

__global__ __launch_bounds__(256) void k_write(const float* __restrict__ pred,
                                               const u32* __restrict__ tilebase,
                                               u64* __restrict__ keys,
                                               int Nn, int Cc, int TIL) {
    int bt = blockIdx.x;
    int tile = bt % TIL, bc = bt / TIL;
    int b = bc / Cc, c = bc % Cc;
    int n = tile * 256 + threadIdx.x;
    bool p = false;
    float sc = 0.f;
    if (n < Nn) {
        float lg = pred[((size_t)b * Nn + n) * 6 + 4 + c];
        sc = __fdiv_rn(1.0f, __fadd_rn(1.0f, expf(-lg)));
        p = sc > CONF;
    }
    u64 m = __ballot(p);
    __shared__ u32 wbase[4];
    int wid = threadIdx.x >> 6, lane = threadIdx.x & 63;
    if (lane == 0) wbase[wid] = (u32)__popcll(m);
    __syncthreads();
    if (threadIdx.x == 0) {
        u32 run = 0;
        for (int i = 0; i < 4; ++i) { u32 t2 = wbase[i]; wbase[i] = run; run += t2; }
    }
    __syncthreads();
    if (p) {
        u32 pos = tilebase[bc * TIL + tile] + wbase[wid] +
                  (u32)__popcll(m & ((1ull << lane) - 1ull));
        if (pos < CAP)
            keys[(size_t)bc * CAP + pos] =
                (((u64)(~__float_as_uint(sc))) << 32) | (u32)n;
    }
}

// bitonic: local full sort of 4096-key tiles in LDS
__global__ __launch_bounds__(1024) void k_sort_local(u64* __restrict__ keys) {
    __shared__ u64 sk[4096];
    u64* a = keys + (size_t)blockIdx.x * 4096;
    int lbase = (blockIdx.x & 7) * 4096;
    for (int i = threadIdx.x; i < 4096; i += 1024) sk[i] = a[i];
    __syncthreads();
    for (int k = 2; k <= 4096; k <<= 1) {
        for (int j = k >> 1; j > 0; j >>= 1) {
            for (int idx = threadIdx.x; idx < 2048; idx += 1024) {
                int i = ((idx & ~(j - 1)) << 1) | (idx & (j - 1));
                int p = i | j;
                bool up = (((lbase + i) & k) == 0);
                u64 x = sk[i], y = sk[p];
                if ((x > y) == up) { sk[i] = y; sk[p] = x; }
            }
            __syncthreads();
        }
    }
    for (int i = threadIdx.x; i < 4096; i += 1024) a[i] = sk[i];
}

// bitonic: one global pass (j >= 4096)
__global__ __launch_bounds__(1024) void k_sort_global(u64* __restrict__ keys, int j, int k) {
    int idx = blockIdx.x * 1024 + threadIdx.x;
    int bc = idx >> 14;
    int lp = idx & 16383;
    int i = ((lp & ~(j - 1)) << 1) | (lp & (j - 1));
    bool up = ((i & k) == 0);
    u64* a = keys + (size_t)bc * CAP;
    u64 x = a[i], y = a[i | j];
    if ((x > y) == up) { a[i] = y; a[i | j] = x; }
}

// bitonic: remaining j<=2048 stages of merge step k, in LDS per 4096-tile
__global__ __launch_bounds__(1024) void k_sort_mergelds(u64* __restrict__ keys, int k) {
    __shared__ u64 sk[4096];
    u64* a = keys + (size_t)blockIdx.x * 4096;
    int lbase = (blockIdx.x & 7) * 4096;
    bool up = ((lbase & k) == 0);
    for (int i = threadIdx.x; i < 4096; i += 1024) sk[i] = a[i];
    __syncthreads();
    for (int j = 2048; j > 0; j >>= 1) {
        for (int idx = threadIdx.x; idx < 2048; idx += 1024) {
            int i = ((idx & ~(j - 1)) << 1) | (idx & (j - 1));
            int p = i | j;
            u64 x = sk[i], y = sk[p];
            if ((x > y) == up) { sk[i] = y; sk[p] = x; }
        }
        __syncthreads();
    }
    for (int i = threadIdx.x; i < 4096; i += 1024) a[i] = sk[i];
}

// Precompute triangular suppression masks for the head HEAD candidates of the list.
// Grid: NBC*16 blocks; block rb covers rows [rb*64, rb*64+64); thread part tid>>6
// covers mask words [part*4, part*4+4). Row r bit j (col=cb+j>r): iou(r, col) > thr.
__global__ __launch_bounds__(256) void k_premask(const u64* __restrict__ list,
                                                 const u32* __restrict__ lcur,
                                                 const float4* __restrict__ boxes,
                                                 const u32* __restrict__ S_arr,
                                                 u64* __restrict__ masks,
                                                 int Nn, int Cc) {
    int blk = blockIdx.x, bc = blk >> 4, rb = blk & 15;
    int len = (int)lcur[bc];
    int S0 = (int)S_arr[bc];
    if (len <= 0 || S0 >= MAXSEL) return;
    int b = bc / Cc;
    int hl = len < HEAD ? len : HEAD;
    __shared__ float4 chB[HEAD];
    __shared__ float  chA[HEAD];
    const u64* kk = list + (size_t)bc * CAP;
    for (int i = threadIdx.x; i < hl; i += 256) {
        float4 bx = boxes[(size_t)b * Nn + (u32)kk[i]];
        chB[i] = bx; chA[i] = areaf(bx);
    }
    __syncthreads();
    int r = (rb << 6) + (threadIdx.x & 63);
    int part = threadIdx.x >> 6;               // 0..3
    if (r >= hl) return;
    float4 a = chB[r]; float aA = chA[r];
    u64* row = masks + ((size_t)bc * HEAD + r) * HW;
    for (int w = part * 4; w < part * 4 + 4; ++w) {
        u64 bits = 0;
        int cb = w << 6;
        int j1 = hl - cb; if (j1 > 64) j1 = 64;
        int j0 = (cb > r) ? 0 : (r + 1 - cb);
        for (int j = j0; j < j1; ++j)
            if (iou_gt2(a, aA, chB[cb + j], chA[cb + j])) bits |= (1ull << j);
        row[w] = bits;
    }
}

// Pure-bitmask greedy chain over the head. Removed mask: lanes 0..15 hold one u64 each.
// Per selection: ballot -> ctz -> shfl -> one conflict-free 16-lane LDS row read -> OR.
// Selection indices recorded to LDS; keys written out after the loop.
__global__ __launch_bounds__(256) void k_chain(const u64* __restrict__ list,
                                               const u32* __restrict__ lcur,
                                               const u64* __restrict__ masks,
                                               u32* __restrict__ sel_n,
                                               float* __restrict__ sel_s,
                                               u32* __restrict__ S_arr,
                                               u32* __restrict__ Sold) {
    int bc = blockIdx.x;
    int tid = threadIdx.x, lane = tid & 63;
    __shared__ u64 mrow[HEAD * HW];   // 128 KB
    __shared__ u64 kky[HEAD];         // 8 KB
    __shared__ u32 selidx[MAXSEL];    // 2.2 KB
    int len = (int)lcur[bc];
    int S0 = (int)S_arr[bc];
    if (tid == 0) Sold[bc] = (u32)S0;
    if (len <= 0 || S0 >= MAXSEL) return;
    int hl = len < HEAD ? len : HEAD;
    const u64* kk = list + (size_t)bc * CAP;
    const u64* gm = masks + (size_t)bc * HEAD * HW;
    for (int i = tid; i < hl * HW; i += 256) mrow[i] = gm[i];
    for (int i = tid; i < hl; i += 256) kky[i] = kk[i];
    __syncthreads();
    if (tid >= 64) return;            // wave 0 only from here (no further barriers)
    u64 rem = ~0ull;
    if (lane < HW) {
        int lo = lane << 6;
        rem = (hl >= lo + 64) ? 0ull : (hl <= lo ? ~0ull : ~((1ull << (hl - lo)) - 1ull));
    }
    int S = S0;
    while (S < MAXSEL) {
        bool av = (lane < HW) && (rem != ~0ull);
        u64 bal = __ballot(av);
        if (!bal) break;
        int w0 = (int)__builtin_ctzll(bal);
        u64 nz = __shfl((u64)(~rem), w0);
        int kz = (int)__builtin_ctzll(nz);
        int i = (w0 << 6) + kz;
        if (lane == 0) selidx[S] = (u32)i;
        if (lane < HW) rem |= mrow[i * HW + lane];
        if (lane == w0) rem |= (1ull << kz);
        ++S;
    }
    for (int s = S0 + lane; s < S; s += 64) {
        u64 k64 = kky[selidx[s]];
        sel_n[bc * MAXSEL + s] = (u32)k64;
        sel_s[bc * MAXSEL + s] = __uint_as_float(~(u32)(k64 >> 32));
    }
    if (lane == 0) S_arr[bc] = (u32)S;
}

// Parallel filter: test remaining candidates [consumed, len) vs selections added this
// round [S0, S1); write alive bitmask + per-segment survivor counts.
__global__ __launch_bounds__(256) void k_mark(const u64* __restrict__ list,
                                              const u32* __restrict__ lcur,
                                              const float4* __restrict__ boxes,
                                              const u32* __restrict__ sel_n,
                                              const u32* __restrict__ S_arr,
                                              const u32* __restrict__ Sold,
                                              u64* __restrict__ amask,
                                              u32* __restrict__ counts,
                                              int Nn, int Cc) {
    int blk = blockIdx.x, bc = blk >> 4, seg = blk & 15;
    int tid = threadIdx.x, lane = tid & 63, wv = tid >> 6;
    int b = bc / Cc;
    int len = (int)lcur[bc];
    int S0 = (int)Sold[bc], S1 = (int)S_arr[bc];
    if (len <= 0 || S0 >= MAXSEL) {
        if (tid == 0) counts[bc * SEG + seg] = 0;
        return;
    }
    int ns = S1 - S0;
    int consumed = len < HEAD ? len : HEAD;
    __shared__ float4 sb[MAXSEL];
    __shared__ float  sa[MAXSEL];
    for (int s = tid; s < ns; s += 256) {
        u32 n = sel_n[bc * MAXSEL + S0 + s];
        float4 v = boxes[(size_t)b * Nn + n];
        sb[s] = v; sa[s] = areaf(v);
    }
    __syncthreads();
    __shared__ u32 wcnt[4];
    u32 mycnt = 0;
    const u64* kk = list + (size_t)bc * CAP;
    for (int r = 0; r < SEGLEN / 256; ++r) {
        int idx = seg * SEGLEN + r * 256 + tid;
        bool alive = (idx >= consumed && idx < len);
        if (alive) {
            u64 key = kk[idx];
            float4 bx = boxes[(size_t)b * Nn + (u32)key];
            float aA = areaf(bx);
            for (int s = 0; s < ns; ++s)
                if (iou_gt2(bx, aA, sb[s], sa[s])) { alive = false; break; }
        }
        u64 bal = __ballot(alive);
        if (lane == 0) {
            amask[(size_t)bc * (CAP / 64) + (idx >> 6)] = bal;
            mycnt += (u32)__popcll(bal);
        }
    }
    if (lane == 0) wcnt[wv] = mycnt;
    __syncthreads();
    if (tid == 0) counts[bc * SEG + seg] = wcnt[0] + wcnt[1] + wcnt[2] + wcnt[3];
}

// Order-preserving compaction of survivors into the other list buffer; updates next llen.
__global__ __launch_bounds__(256) void k_cwrite(const u64* __restrict__ cur,
                                                u64* __restrict__ nxt,
                                                u32* __restrict__ lnxt,
                                                const u64* __restrict__ amask,
                                                const u32* __restrict__ counts) {
    int blk = blockIdx.x, bc = blk >> 4, seg = blk & 15;
    int tid = threadIdx.x, lane = tid & 63, wv = tid >> 6;
    __shared__ u32 sbase, stot;
    __shared__ u32 wb[4];
    if (tid == 0) {
        u32 base = 0, tot = 0;
        for (int s = 0; s < SEG; ++s) {
            u32 v = counts[bc * SEG + s];
            if (s < seg) base += v;
            tot += v;
        }
        sbase = base; stot = tot;
        if (seg == 0) lnxt[bc] = tot;
    }
    __syncthreads();
    if (stot == 0) return;
    u32 run = sbase;
    const u64* src = cur + (size_t)bc * CAP;
    u64* dst = nxt + (size_t)bc * CAP;
    for (int r = 0; r < SEGLEN / 256; ++r) {
        int idx = seg * SEGLEN + r * 256 + tid;
        u64 w = amask[(size_t)bc * (CAP / 64) + (idx >> 6)];
        bool alive = (w >> lane) & 1ull;
        if (lane == 0) wb[wv] = (u32)__popcll(w);
        __syncthreads();
        u32 wpre = 0;
        #pragma unroll
        for (int i = 0; i < 4; ++i) if (i < wv) wpre += wb[i];
        if (alive) {
            u32 rank = (u32)__popcll(w & ((1ull << lane) - 1ull));
            dst[run + wpre + rank] = src[idx];
        }
        u32 tot = wb[0] + wb[1] + wb[2] + wb[3];
        __syncthreads();
        run += tot;
    }
}

// final: per-batch full sort of C*550 entries (== top_k) + output write
__global__ __launch_bounds__(1024) void k_final(const u32* __restrict__ selcnt,
                                                const u32* __restrict__ sel_n,
                                                const float* __restrict__ sel_s,
                                                const float4* __restrict__ boxes,
                                                float* __restrict__ out,
                                                int Nn, int Cc, int Bb) {
    int b = blockIdx.x, tid = threadIdx.x;
    const int TOT = MAXSEL * 2;   // 1100
    __shared__ u64 sk[2048];
    u32 c0 = selcnt[b * Cc + 0];
    u32 c1 = selcnt[b * Cc + 1];
    for (int t = tid; t < 2048; t += 1024) {
        u64 key;
        if (t < TOT) {
            int c = t / MAXSEL, k2 = t % MAXSEL;
            u32 cc = (c == 0) ? c0 : c1;
            float sc = (k2 < (int)cc) ? sel_s[(size_t)(b * Cc + c) * MAXSEL + k2] : NEGV;
            u32 u = __float_as_uint(sc);
            u32 ord = (u & 0x80000000u) ? ~u : (u | 0x80000000u);
            key = (((u64)(~ord)) << 32) | (u32)t;
        } else {
            key = ~0ull;
        }
        sk[t] = key;
    }
    __syncthreads();
    for (int k = 2; k <= 2048; k <<= 1) {
        for (int j = k >> 1; j > 0; j >>= 1) {
            int idx = tid;
            int i = ((idx & ~(j - 1)) << 1) | (idx & (j - 1));
            int p = i | j;
            bool up = ((i & k) == 0);
            u64 x = sk[i], y = sk[p];
            if ((x > y) == up) { sk[i] = y; sk[p] = x; }
            __syncthreads();
        }
    }
    int off_scores = Bb * TOT * 4;
    int off_classes = off_scores + Bb * TOT;
    int off_valid = off_classes + Bb * TOT;
    for (int r = tid; r < TOT; r += 1024) {
        u64 key = sk[r];
        u32 flat = (u32)(key & 0xffffffffull);
        u32 hi = (u32)(key >> 32);
        u32 ord = ~hi;
        float sc = (ord & 0x80000000u) ? __uint_as_float(ord & 0x7fffffffu)
                                       : __uint_as_float(~ord);
        bool valid = sc > -5.0e8f;
        int c = (int)(flat / MAXSEL), k2 = (int)(flat % MAXSEL);
        float4 bxv = make_float4(0.f, 0.f, 0.f, 0.f);
        float so = 0.f, co = 0.f;
        if (valid) {
            u32 n = sel_n[(size_t)(b * Cc + c) * MAXSEL + k2];
            bxv = boxes[(size_t)b * Nn + n];
            so = sc;
            co = (float)c;
        }
        ((float4*)out)[b * TOT + r] = bxv;
        out[off_scores + b * TOT + r] = so;
        out[off_classes + b * TOT + r] = co;
    }
    if (tid == 0) out[off_valid + b] = (float)(c0 + c1);
}

extern "C" void kernel_launch(void* const* d_in, const int* in_sizes, int n_in,
                              void* d_out, int out_size, void* d_ws, size_t ws_size,
                              hipStream_t stream) {
    const float* pred = (const float*)d_in[1];
    float* out = (float*)d_out;
    int Bb = out_size / 6601;            // 4
    int Nn = in_sizes[1] / (6 * Bb);     // 49104
    const int Cc = 2;
    if (Bb <= 0 || Nn <= 0) return;
    int NBC = Bb * Cc;                   // 8
    int TIL = (Nn + 255) / 256;          // 192

    char* ws = (char*)d_ws;
    size_t off = 0;
    auto alloc = [&](size_t bytes) { void* p = ws + off; off = (off + bytes + 255) & ~(size_t)255; return p; };
    float4* boxes   = (float4*)alloc((size_t)Bb * Nn * 16);
    u64* L0         = (u64*)alloc((size_t)NBC * CAP * 8);
    u64* L1         = (u64*)alloc((size_t)NBC * CAP * 8);
    u32* llen       = (u32*)alloc(2 * NBC * 4);            // ping-pong lengths
    u32* tilecnt    = (u32*)alloc((size_t)NBC * TIL * 4);
    u32* tilebase   = (u32*)alloc((size_t)NBC * TIL * 4);
    u32* sel_n      = (u32*)alloc((size_t)NBC * MAXSEL * 4);
    float* sel_s    = (float*)alloc((size_t)NBC * MAXSEL * 4);
    u32* S_arr      = (u32*)alloc(NBC * 4);
    u32* Sold       = (u32*)alloc(NBC * 4);
    u64* masks      = (u64*)alloc((size_t)NBC * HEAD * HW * 8);   // 1 MB
    u64* amask      = (u64*)alloc((size_t)NBC * (CAP / 64) * 8);
    u32* counts     = (u32*)alloc((size_t)NBC * SEG * 4);
    if (off > ws_size) return;

    int BN = Bb * Nn;
    k_init<<<NBC * CAP / 256, 256, 0, stream>>>(L0, S_arr, Sold, NBC);
    k_decode<<<(BN + 255) / 256, 256, 0, stream>>>(pred, boxes, BN);
    k_cnt<<<NBC * TIL, 256, 0, stream>>>(pred, tilecnt, Nn, Cc, TIL);
    k_scan<<<1, 64, 0, stream>>>(tilecnt, tilebase, llen, TIL, NBC);
    k_write<<<NBC * TIL, 256, 0, stream>>>(pred, tilebase, L0, Nn, Cc, TIL);

    int ntiles = NBC * (CAP / 4096);     // 64
    k_sort_local<<<ntiles, 1024, 0, stream>>>(L0);
    for (int k = 8192; k <= CAP; k <<= 1) {
        for (int j = k >> 1; j >= 4096; j >>= 1)
            k_sort_global<<<NBC * (CAP / 2) / 1024, 1024, 0, stream>>>(L0, j, k);
        k_sort_mergelds<<<ntiles, 1024, 0, stream>>>(L0, k);
    }

    for (int r = 0; r < TROUNDS; ++r) {
        u64* cur = (r & 1) ? L1 : L0;
        u64* nxt = (r & 1) ? L0 : L1;
        u32* lcur = llen + (r & 1) * NBC;
        u32* lnxt = llen + ((r + 1) & 1) * NBC;
        k_premask<<<NBC * 16, 256, 0, stream>>>(cur, lcur, boxes, S_arr, masks, Nn, Cc);
        k_chain<<<NBC, 256, 0, stream>>>(cur, lcur, masks, sel_n, sel_s, S_arr, Sold);
        k_mark<<<NBC * SEG, 256, 0, stream>>>(cur, lcur, boxes, sel_n, S_arr, Sold, amask, counts, Nn, Cc);
        k_cwrite<<<NBC * SEG, 256, 0, stream>>>(cur, nxt, lnxt, amask, counts);
    }
    k_final<<<Bb, 1024, 0, stream>>>(S_arr, sel_n, sel_s, boxes, out, Nn, Cc, Bb);
}

// Round 7
// 371.564 us; speedup vs baseline: 11.7620x; 1.4779x over previous
//
#include <hip/hip_runtime.h>
#include <stdint.h>

#define NEGV    (-1000000000.0f)
#define CONF    0.05f
#define MAXSEL  550
#define CAP     32768
#define HEAD    1024
#define HW      (HEAD / 64)    // 16 mask words per row
#define SEG     64
#define SEGLEN  (CAP / SEG)    // 512
#define TROUNDS 5

typedef unsigned long long u64;
typedef unsigned int u32;

__device__ __forceinline__ float areaf(float4 b) {
    return __fmul_rn(fmaxf(__fsub_rn(b.z, b.x), 0.0f), fmaxf(__fsub_rn(b.w, b.y), 0.0f));
}

// Exact predicate for: __fdiv_rn(inter, max(uni,1e-8)) > 0.15f  (verified absmax 0 since R4).
// q_rn > 0.15f  <=>  exact quotient > M, M = midpoint(0.15f, next(0.15f)) = 0.15f + 2^-27.
// inter (24b) * M (25b) exact in double; comparison exact. No v_div sequence. Symmetric in (a,b).
__device__ __forceinline__ bool iou_gt2(float4 a, float aA, float4 b, float aB) {
    float ltx = fmaxf(a.x, b.x), lty = fmaxf(a.y, b.y);
    float rbx = fminf(a.z, b.z), rby = fminf(a.w, b.w);
    float wx = fmaxf(__fsub_rn(rbx, ltx), 0.0f);
    float wy = fmaxf(__fsub_rn(rby, lty), 0.0f);
    float inter = __fmul_rn(wx, wy);
    float uni = fmaxf(__fsub_rn(__fadd_rn(aA, aB), inter), 1e-8f);
    const double M = (double)0.15f + 0x1p-27;
    return (double)inter > M * (double)uni;
}

__global__ void k_decode(const float* __restrict__ pred, float4* __restrict__ boxes, int BN) {
    int t = blockIdx.x * 256 + threadIdx.x;
    if (t >= BN) return;
    const float* p = pred + (size_t)t * 6;
    float cx = p[0], cy = p[1], w = p[2], h = p[3];
    float hw = __fmul_rn(w, 0.5f), hh = __fmul_rn(h, 0.5f);
    float4 b;
    b.x = __fsub_rn(cx, hw);
    b.y = __fsub_rn(cy, hh);
    b.z = __fadd_rn(cx, hw);
    b.w = __fadd_rn(cy, hh);
    boxes[t] = b;
}

__global__ void k_init(u64* __restrict__ keys, u32* __restrict__ S_arr,
                       u32* __restrict__ Sold, int NBC) {
    int t = blockIdx.x * 256 + threadIdx.x;
    keys[t] = ~0ull;
    if (t < NBC) { S_arr[t] = 0; Sold[t] = 0; }
}

// parallel compaction: count per 256-tile
__global__ __launch_bounds__(256) void k_cnt(const float* __restrict__ pred,
                                             u32* __restrict__ tilecnt,
                                             int Nn, int Cc, int TIL) {
    int bt = blockIdx.x;
    int tile = bt % TIL, bc = bt / TIL;
    int b = bc / Cc, c = bc % Cc;
    int n = tile * 256 + threadIdx.x;
    bool p = false;
    if (n < Nn) {
        float lg = pred[((size_t)b * Nn + n) * 6 + 4 + c];
        float sc = __fdiv_rn(1.0f, __fadd_rn(1.0f, expf(-lg)));
        p = sc > CONF;
    }
    u64 m = __ballot(p);
    __shared__ u32 wsum[4];
    if ((threadIdx.x & 63) == 0) wsum[threadIdx.x >> 6] = (u32)__popcll(m);
    __syncthreads();
    if (threadIdx.x == 0) tilecnt[bc * TIL + tile] = wsum[0] + wsum[1] + wsum[2] + wsum[3];
}

__global__ void k_scan(const u32* __restrict__ tilecnt, u32* __restrict__ tilebase,
                       u32* __restrict__ llen0, int TIL, int NBC) {
    int bc = threadIdx.x;
    if (bc < NBC) {
        u32 run = 0;
        for (int t = 0; t < TIL; ++t) { tilebase[bc * TIL + t] = run; run += tilecnt[bc * TIL + t]; }
        llen0[bc] = run < CAP ? run : CAP;
    }
}

__global__ __launch_bounds__(256) void k_write(const float* __restrict__ pred,
                                               const u32* __restrict__ tilebase,
                                               u64* __restrict__ keys,
                                               int Nn, int Cc, int TIL) {
    int bt = blockIdx.x;
    int tile = bt % TIL, bc = bt / TIL;
    int b = bc / Cc, c = bc % Cc;
    int n = tile * 256 + threadIdx.x;
    bool p = false;
    float sc = 0.f;
    if (n < Nn) {
        float lg = pred[((size_t)b * Nn + n) * 6 + 4 + c];
        sc = __fdiv_rn(1.0f, __fadd_rn(1.0f, expf(-lg)));
        p = sc > CONF;
    }
    u64 m = __ballot(p);
    __shared__ u32 wbase[4];
    int wid = threadIdx.x >> 6, lane = threadIdx.x & 63;
    if (lane == 0) wbase[wid] = (u32)__popcll(m);
    __syncthreads();
    if (threadIdx.x == 0) {
        u32 run = 0;
        for (int i = 0; i < 4; ++i) { u32 t2 = wbase[i]; wbase[i] = run; run += t2; }
    }
    __syncthreads();
    if (p) {
        u32 pos = tilebase[bc * TIL + tile] + wbase[wid] +
                  (u32)__popcll(m & ((1ull << lane) - 1ull));
        if (pos < CAP)
            keys[(size_t)bc * CAP + pos] =
                (((u64)(~__float_as_uint(sc))) << 32) | (u32)n;
    }
}

// bitonic: local full sort of 4096-key tiles in LDS
__global__ __launch_bounds__(1024) void k_sort_local(u64* __restrict__ keys) {
    __shared__ u64 sk[4096];
    u64* a = keys + (size_t)blockIdx.x * 4096;
    int lbase = (blockIdx.x & 7) * 4096;
    for (int i = threadIdx.x; i < 4096; i += 1024) sk[i] = a[i];
    __syncthreads();
    for (int k = 2; k <= 4096; k <<= 1) {
        for (int j = k >> 1; j > 0; j >>= 1) {
            for (int idx = threadIdx.x; idx < 2048; idx += 1024) {
                int i = ((idx & ~(j - 1)) << 1) | (idx & (j - 1));
                int p = i | j;
                bool up = (((lbase + i) & k) == 0);
                u64 x = sk[i], y = sk[p];
                if ((x > y) == up) { sk[i] = y; sk[p] = x; }
            }
            __syncthreads();
        }
    }
    for (int i = threadIdx.x; i < 4096; i += 1024) a[i] = sk[i];
}

// bitonic: one global pass (j >= 4096)
__global__ __launch_bounds__(1024) void k_sort_global(u64* __restrict__ keys, int j, int k) {
    int idx = blockIdx.x * 1024 + threadIdx.x;
    int bc = idx >> 14;
    int lp = idx & 16383;
    int i = ((lp & ~(j - 1)) << 1) | (lp & (j - 1));
    bool up = ((i & k) == 0);
    u64* a = keys + (size_t)bc * CAP;
    u64 x = a[i], y = a[i | j];
    if ((x > y) == up) { a[i] = y; a[i | j] = x; }
}

// bitonic: remaining j<=2048 stages of merge step k, in LDS per 4096-tile
__global__ __launch_bounds__(1024) void k_sort_mergelds(u64* __restrict__ keys, int k) {
    __shared__ u64 sk[4096];
    u64* a = keys + (size_t)blockIdx.x * 4096;
    int lbase = (blockIdx.x & 7) * 4096;
    bool up = ((lbase & k) == 0);
    for (int i = threadIdx.x; i < 4096; i += 1024) sk[i] = a[i];
    __syncthreads();
    for (int j = 2048; j > 0; j >>= 1) {
        for (int idx = threadIdx.x; idx < 2048; idx += 1024) {
            int i = ((idx & ~(j - 1)) << 1) | (idx & (j - 1));
            int p = i | j;
            u64 x = sk[i], y = sk[p];
            if ((x > y) == up) { sk[i] = y; sk[p] = x; }
        }
        __syncthreads();
    }
    for (int i = threadIdx.x; i < 4096; i += 1024) a[i] = sk[i];
}

// Precompute triangular suppression masks for the head HEAD candidates of the list.
__global__ __launch_bounds__(256) void k_premask(const u64* __restrict__ list,
                                                 const u32* __restrict__ lcur,
                                                 const float4* __restrict__ boxes,
                                                 const u32* __restrict__ S_arr,
                                                 u64* __restrict__ masks,
                                                 int Nn, int Cc) {
    int blk = blockIdx.x, bc = blk >> 4, rb = blk & 15;
    int len = (int)lcur[bc];
    int S0 = (int)S_arr[bc];
    if (len <= 0 || S0 >= MAXSEL) return;
    int b = bc / Cc;
    int hl = len < HEAD ? len : HEAD;
    __shared__ float4 chB[HEAD];
    __shared__ float  chA[HEAD];
    const u64* kk = list + (size_t)bc * CAP;
    for (int i = threadIdx.x; i < hl; i += 256) {
        float4 bx = boxes[(size_t)b * Nn + (u32)kk[i]];
        chB[i] = bx; chA[i] = areaf(bx);
    }
    __syncthreads();
    int r = (rb << 6) + (threadIdx.x & 63);
    int part = threadIdx.x >> 6;               // 0..3
    if (r >= hl) return;
    float4 a = chB[r]; float aA = chA[r];
    u64* row = masks + ((size_t)bc * HEAD + r) * HW;
    for (int w = part * 4; w < part * 4 + 4; ++w) {
        u64 bits = 0;
        int cb = w << 6;
        int j1 = hl - cb; if (j1 > 64) j1 = 64;
        int j0 = (cb > r) ? 0 : (r + 1 - cb);
        for (int j = j0; j < j1; ++j)
            if (iou_gt2(a, aA, chB[cb + j], chA[cb + j])) bits |= (1ull << j);
        row[w] = bits;
    }
}

// Pure-bitmask greedy chain over the head (wave 0), 1024 threads for fast mask staging.
// Tail (all threads): gather compact selected-box arrays selb_g/sela_g for this round.
__global__ __launch_bounds__(1024) void k_chain(const u64* __restrict__ list,
                                                const u32* __restrict__ lcur,
                                                const u64* __restrict__ masks,
                                                const float4* __restrict__ boxes,
                                                u32* __restrict__ sel_n,
                                                float* __restrict__ sel_s,
                                                float4* __restrict__ selb_g,
                                                float* __restrict__ sela_g,
                                                u32* __restrict__ S_arr,
                                                u32* __restrict__ Sold,
                                                int Nn, int Cc) {
    int bc = blockIdx.x, b = bc / Cc;
    int tid = threadIdx.x, lane = tid & 63;
    __shared__ u64 mrow[HEAD * HW];   // 128 KB
    __shared__ u64 kky[HEAD];         // 8 KB
    __shared__ u32 selidx[MAXSEL];    // 2.2 KB
    __shared__ int s_S;
    int len = (int)lcur[bc];
    int S0 = (int)S_arr[bc];
    if (tid == 0) Sold[bc] = (u32)S0;
    if (len <= 0 || S0 >= MAXSEL) return;   // uniform
    int hl = len < HEAD ? len : HEAD;
    const u64* kk = list + (size_t)bc * CAP;
    const u64* gm = masks + (size_t)bc * HEAD * HW;
    for (int i = tid; i < hl * HW; i += 1024) mrow[i] = gm[i];
    for (int i = tid; i < hl; i += 1024) kky[i] = kk[i];
    __syncthreads();
    if (tid < 64) {                   // wave 0 walks
        u64 rem = ~0ull;
        if (lane < HW) {
            int lo = lane << 6;
            rem = (hl >= lo + 64) ? 0ull : (hl <= lo ? ~0ull : ~((1ull << (hl - lo)) - 1ull));
        }
        int S = S0;
        while (S < MAXSEL) {
            bool av = (lane < HW) && (rem != ~0ull);
            u64 bal = __ballot(av);
            if (!bal) break;
            int w0 = (int)__builtin_ctzll(bal);
            u64 nz = __shfl((u64)(~rem), w0);
            int kz = (int)__builtin_ctzll(nz);
            int i = (w0 << 6) + kz;
            if (lane == 0) selidx[S] = (u32)i;
            if (lane < HW) rem |= mrow[i * HW + lane];
            if (lane == w0) rem |= (1ull << kz);
            ++S;
        }
        if (lane == 0) { s_S = S; S_arr[bc] = (u32)S; }
    }
    __syncthreads();
    int S = s_S;
    for (int s = S0 + tid; s < S; s += 1024) {
        u64 k64 = kky[selidx[s]];
        u32 n = (u32)k64;
        sel_n[bc * MAXSEL + s] = n;
        sel_s[bc * MAXSEL + s] = __uint_as_float(~(u32)(k64 >> 32));
        float4 bx = boxes[(size_t)b * Nn + n];
        selb_g[bc * MAXSEL + s] = bx;
        sela_g[bc * MAXSEL + s] = areaf(bx);
    }
}

// Parallel filter: test remaining candidates [consumed, len) vs selections added this
// round [S0, S1). Skips entirely (kills list) when S1 >= MAXSEL: no future selections.
__global__ __launch_bounds__(256) void k_mark(const u64* __restrict__ list,
                                              const u32* __restrict__ lcur,
                                              const float4* __restrict__ boxes,
                                              const float4* __restrict__ selb_g,
                                              const float* __restrict__ sela_g,
                                              const u32* __restrict__ S_arr,
                                              const u32* __restrict__ Sold,
                                              u64* __restrict__ amask,
                                              u32* __restrict__ counts,
                                              int Nn, int Cc) {
    int blk = blockIdx.x, bc = blk >> 6, seg = blk & 63;
    int tid = threadIdx.x, lane = tid & 63, wv = tid >> 6;
    int b = bc / Cc;
    int len = (int)lcur[bc];
    int S0 = (int)Sold[bc], S1 = (int)S_arr[bc];
    if (len <= 0 || S0 >= MAXSEL || S1 >= MAXSEL) {   // complete or empty: kill list
        if (tid == 0) counts[bc * SEG + seg] = 0;
        return;
    }
    int ns = S1 - S0;
    int consumed = len < HEAD ? len : HEAD;
    __shared__ float4 sb[MAXSEL];
    __shared__ float  sa[MAXSEL];
    for (int s = tid; s < ns; s += 256) {
        sb[s] = selb_g[bc * MAXSEL + S0 + s];
        sa[s] = sela_g[bc * MAXSEL + S0 + s];
    }
    __syncthreads();
    __shared__ u32 wcnt[4];
    u32 mycnt = 0;
    const u64* kk = list + (size_t)bc * CAP;
    int n4 = ns & ~3;
    for (int r = 0; r < SEGLEN / 256; ++r) {
        int idx = seg * SEGLEN + r * 256 + tid;
        bool alive = (idx >= consumed && idx < len);
        if (alive) {
            u64 key = kk[idx];
            float4 bx = boxes[(size_t)b * Nn + (u32)key];
            float aA = areaf(bx);
            bool dead = false;
            int s = 0;
            for (; s < n4; s += 4) {     // 4-wide ILP, group-granularity early break
                bool h = iou_gt2(bx, aA, sb[s], sa[s]) |
                         iou_gt2(bx, aA, sb[s + 1], sa[s + 1]) |
                         iou_gt2(bx, aA, sb[s + 2], sa[s + 2]) |
                         iou_gt2(bx, aA, sb[s + 3], sa[s + 3]);
                if (h) { dead = true; break; }
            }
            if (!dead)
                for (; s < ns; ++s)
                    if (iou_gt2(bx, aA, sb[s], sa[s])) { dead = true; break; }
            alive = !dead;
        }
        u64 bal = __ballot(alive);
        if (lane == 0) {
            amask[(size_t)bc * (CAP / 64) + (idx >> 6)] = bal;
            mycnt += (u32)__popcll(bal);
        }
    }
    if (lane == 0) wcnt[wv] = mycnt;
    __syncthreads();
    if (tid == 0) counts[bc * SEG + seg] = wcnt[0] + wcnt[1] + wcnt[2] + wcnt[3];
}

// Order-preserving compaction of survivors into the other list buffer; updates next llen.
__global__ __launch_bounds__(256) void k_cwrite(const u64* __restrict__ cur,
                                                u64* __restrict__ nxt,
                                                u32* __restrict__ lnxt,
                                                const u64* __restrict__ amask,
                                                const u32* __restrict__ counts) {
    int blk = blockIdx.x, bc = blk >> 6, seg = blk & 63;
    int tid = threadIdx.x, lane = tid & 63, wv = tid >> 6;
    __shared__ u32 sbase, stot;
    __shared__ u32 wb[4];
    if (tid < 64) {   // wave-parallel exclusive prefix over this bc's 64 segment counts
        u32 v = counts[bc * SEG + tid];
        u32 p = v;
        for (int d = 1; d < 64; d <<= 1) {
            u32 o = __shfl_up(p, d);
            if (tid >= d) p += o;
        }
        if (tid == seg) sbase = p - v;
        if (tid == 63) { stot = p; if (seg == 0) lnxt[bc] = p; }
    }
    __syncthreads();
    if (stot == 0) return;
    u32 run = sbase;
    const u64* src = cur + (size_t)bc * CAP;
    u64* dst = nxt + (size_t)bc * CAP;
    for (int r = 0; r < SEGLEN / 256; ++r) {
        int idx = seg * SEGLEN + r * 256 + tid;
        u64 w = amask[(size_t)bc * (CAP / 64) + (idx >> 6)];
        bool alive = (w >> lane) & 1ull;
        if (lane == 0) wb[wv] = (u32)__popcll(w);
        __syncthreads();
        u32 wpre = 0;
        #pragma unroll
        for (int i = 0; i < 4; ++i) if (i < wv) wpre += wb[i];
        if (alive) {
            u32 rank = (u32)__popcll(w & ((1ull << lane) - 1ull));
            dst[run + wpre + rank] = src[idx];
        }
        u32 tot = wb[0] + wb[1] + wb[2] + wb[3];
        __syncthreads();
        run += tot;
    }
}

// final: per-batch full sort of C*550 entries (== top_k) + output write
__global__ __launch_bounds__(1024) void k_final(const u32* __restrict__ selcnt,
                                                const u32* __restrict__ sel_n,
                                                const float* __restrict__ sel_s,
                                                const float4* __restrict__ boxes,
                                                float* __restrict__ out,
                                                int Nn, int Cc, int Bb) {
    int b = blockIdx.x, tid = threadIdx.x;
    const int TOT = MAXSEL * 2;   // 1100
    __shared__ u64 sk[2048];
    u32 c0 = selcnt[b * Cc + 0];
    u32 c1 = selcnt[b * Cc + 1];
    for (int t = tid; t < 2048; t += 1024) {
        u64 key;
        if (t < TOT) {
            int c = t / MAXSEL, k2 = t % MAXSEL;
            u32 cc = (c == 0) ? c0 : c1;
            float sc = (k2 < (int)cc) ? sel_s[(size_t)(b * Cc + c) * MAXSEL + k2] : NEGV;
            u32 u = __float_as_uint(sc);
            u32 ord = (u & 0x80000000u) ? ~u : (u | 0x80000000u);
            key = (((u64)(~ord)) << 32) | (u32)t;
        } else {
            key = ~0ull;
        }
        sk[t] = key;
    }
    __syncthreads();
    for (int k = 2; k <= 2048; k <<= 1) {
        for (int j = k >> 1; j > 0; j >>= 1) {
            int idx = tid;
            int i = ((idx & ~(j - 1)) << 1) | (idx & (j - 1));
            int p = i | j;
            bool up = ((i & k) == 0);
            u64 x = sk[i], y = sk[p];
            if ((x > y) == up) { sk[i] = y; sk[p] = x; }
            __syncthreads();
        }
    }
    int off_scores = Bb * TOT * 4;
    int off_classes = off_scores + Bb * TOT;
    int off_valid = off_classes + Bb * TOT;
    for (int r = tid; r < TOT; r += 1024) {
        u64 key = sk[r];
        u32 flat = (u32)(key & 0xffffffffull);
        u32 hi = (u32)(key >> 32);
        u32 ord = ~hi;
        float sc = (ord & 0x80000000u) ? __uint_as_float(ord & 0x7fffffffu)
                                       : __uint_as_float(~ord);
        bool valid = sc > -5.0e8f;
        int c = (int)(flat / MAXSEL), k2 = (int)(flat % MAXSEL);
        float4 bxv = make_float4(0.f, 0.f, 0.f, 0.f);
        float so = 0.f, co = 0.f;
        if (valid) {
            u32 n = sel_n[(size_t)(b * Cc + c) * MAXSEL + k2];
            bxv = boxes[(size_t)b * Nn + n];
            so = sc;
            co = (float)c;
        }
        ((float4*)out)[b * TOT + r] = bxv;
        out[off_scores + b * TOT + r] = so;
        out[off_classes + b * TOT + r] = co;
    }
    if (tid == 0) out[off_valid + b] = (float)(c0 + c1);
}

extern "C" void kernel_launch(void* const* d_in, const int* in_sizes, int n_in,
                              void* d_out, int out_size, void* d_ws, size_t ws_size,
                              hipStream_t stream) {
    const float* pred = (const float*)d_in[1];
    float* out = (float*)d_out;
    int Bb = out_size / 6601;            // 4
    int Nn = in_sizes[1] / (6 * Bb);     // 49104
    const int Cc = 2;
    if (Bb <= 0 || Nn <= 0) return;
    int NBC = Bb * Cc;                   // 8
    int TIL = (Nn + 255) / 256;          // 192

    char* ws = (char*)d_ws;
    size_t off = 0;
    auto alloc = [&](size_t bytes) { void* p = ws + off; off = (off + bytes + 255) & ~(size_t)255; return p; };
    float4* boxes   = (float4*)alloc((size_t)Bb * Nn * 16);
    u64* L0         = (u64*)alloc((size_t)NBC * CAP * 8);
    u64* L1         = (u64*)alloc((size_t)NBC * CAP * 8);
    u32* llen       = (u32*)alloc(2 * NBC * 4);            // ping-pong lengths
    u32* tilecnt    = (u32*)alloc((size_t)NBC * TIL * 4);
    u32* tilebase   = (u32*)alloc((size_t)NBC * TIL * 4);
    u32* sel_n      = (u32*)alloc((size_t)NBC * MAXSEL * 4);
    float* sel_s    = (float*)alloc((size_t)NBC * MAXSEL * 4);
    float4* selb_g  = (float4*)alloc((size_t)NBC * MAXSEL * 16);
    float* sela_g   = (float*)alloc((size_t)NBC * MAXSEL * 4);
    u32* S_arr      = (u32*)alloc(NBC * 4);
    u32* Sold       = (u32*)alloc(NBC * 4);
    u64* masks      = (u64*)alloc((size_t)NBC * HEAD * HW * 8);   // 1 MB
    u64* amask      = (u64*)alloc((size_t)NBC * (CAP / 64) * 8);
    u32* counts     = (u32*)alloc((size_t)NBC * SEG * 4);
    if (off > ws_size) return;

    int BN = Bb * Nn;
    k_init<<<NBC * CAP / 256, 256, 0, stream>>>(L0, S_arr, Sold, NBC);
    k_decode<<<(BN + 255) / 256, 256, 0, stream>>>(pred, boxes, BN);
    k_cnt<<<NBC * TIL, 256, 0, stream>>>(pred, tilecnt, Nn, Cc, TIL);
    k_scan<<<1, 64, 0, stream>>>(tilecnt, tilebase, llen, TIL, NBC);
    k_write<<<NBC * TIL, 256, 0, stream>>>(pred, tilebase, L0, Nn, Cc, TIL);

    int ntiles = NBC * (CAP / 4096);     // 64
    k_sort_local<<<ntiles, 1024, 0, stream>>>(L0);
    for (int k = 8192; k <= CAP; k <<= 1) {
        for (int j = k >> 1; j >= 4096; j >>= 1)
            k_sort_global<<<NBC * (CAP / 2) / 1024, 1024, 0, stream>>>(L0, j, k);
        k_sort_mergelds<<<ntiles, 1024, 0, stream>>>(L0, k);
    }

    for (int r = 0; r < TROUNDS; ++r) {
        u64* cur = (r & 1) ? L1 : L0;
        u64* nxt = (r & 1) ? L0 : L1;
        u32* lcur = llen + (r & 1) * NBC;
        u32* lnxt = llen + ((r + 1) & 1) * NBC;
        k_premask<<<NBC * 16, 256, 0, stream>>>(cur, lcur, boxes, S_arr, masks, Nn, Cc);
        k_chain<<<NBC, 1024, 0, stream>>>(cur, lcur, masks, boxes, sel_n, sel_s,
                                          selb_g, sela_g, S_arr, Sold, Nn, Cc);
        k_mark<<<NBC * SEG, 256, 0, stream>>>(cur, lcur, boxes, selb_g, sela_g,
                                              S_arr, Sold, amask, counts, Nn, Cc);
        k_cwrite<<<NBC * SEG, 256, 0, stream>>>(cur, nxt, lnxt, amask, counts);
    }
    k_final<<<Bb, 1024, 0, stream>>>(S_arr, sel_n, sel_s, boxes, out, Nn, Cc, Bb);
}